// Round 11
// baseline (2149.682 us; speedup 1.0000x reference)
//
#include <hip/hip_runtime.h>
#include <math.h>

#define BSZ 512
#define NV 30
#define NT 24
#define SS 768                  // state row stride (x: 0..249, m: 250..749, pad: 750..767)
#define PL (80 * 24 * 512)      // packed ushorts per (layer, half): 80 nb-blocks x 24 kc x 512
#define NBLK 256
#define NSTEP 144

typedef __attribute__((ext_vector_type(8))) short bf16x8;
typedef __attribute__((ext_vector_type(4))) float f32x4;
typedef __attribute__((ext_vector_type(4))) unsigned u32x4;

__device__ __forceinline__ unsigned short f2bf(float f) {
    unsigned u = __float_as_uint(f);
    u += 0x7fffu + ((u >> 16) & 1u);        // round-to-nearest-even
    return (unsigned short)(u >> 16);
}
__device__ __forceinline__ float bf2f(unsigned short h) {
    return __uint_as_float(((unsigned)h) << 16);
}
__device__ __forceinline__ f32x4 mm(bf16x8 a, bf16x8 b, f32x4 c) {
    return __builtin_amdgcn_mfma_f32_16x16x32_bf16(a, b, c, 0, 0, 0);
}
#define LD8(p) (*(const bf16x8*)(const void*)(p))

// coalesced 16B load, L1-bypass (sc0); result valid only after explicit vmcnt fence.
__device__ __forceinline__ u32x4 ld16_sc0(const void* p) {
    u32x4 r;
    asm volatile("global_load_dwordx4 %0, %1, off sc0" : "=v"(r) : "v"(p) : "memory");
    return r;
}

struct RecArgs {
    const unsigned short* Pw;
    unsigned* A0; unsigned* A1;      // interleaved state planes: elem = hi | (lo<<16)
    float* Sfin;
    unsigned int* cnt;               // per-XCD barrier counters, stride 32 u32
    unsigned int* rel;               // per-XCD release words, stride 32 u32
    unsigned int* ticket;            // per-XCD tickets [8]
    const float* b1_sw; const float* b1_mem; const float* b1_sv;
    const float* b_sw;  const float* b_mem;  const float* b_sv;
    const float* w1_sw; const float* w1_mem; const float* w1_sv;
    const int* letters;
};

// ---------------- zero ----------------
__global__ void zero_kernel(float* p, int n) {
    int i = blockIdx.x * blockDim.x + threadIdx.x;
    int st = gridDim.x * blockDim.x;
    for (; i < n; i += st) p[i] = 0.f;
}

// ---------------- one-time weight pack: fp32 [750][N] -> hi/lo bf16 MFMA-B layout ----------------
// Phi[((nb*24 + kc)*64 + lane)*8 + j] = bf16_hi(W[kc*32 + (lane>>4)*8 + j][nb*16 + (lane&15)])
// nb 0..31 = sw (N=500 pad 512), 32..63 = mem, 64..79 = sv (N=250 pad 256). k>=750 zero-padded.
__launch_bounds__(64)
__global__ void pack_weights(const float* __restrict__ Wsw, const float* __restrict__ Wmem,
                             const float* __restrict__ Wsv,
                             unsigned short* __restrict__ Phi, unsigned short* __restrict__ Plo)
{
    const int kc = blockIdx.x;   // 0..23
    const int nb = blockIdx.y;   // 0..79
    const int l  = threadIdx.x;  // 0..63
    const int g = l >> 4, c = l & 15;
    const float* W; int N, nbl;
    if (nb < 32)      { W = Wsw;  N = 500; nbl = nb; }
    else if (nb < 64) { W = Wmem; N = 500; nbl = nb - 32; }
    else              { W = Wsv;  N = 250; nbl = nb - 64; }
    const int n = nbl * 16 + c;
    unsigned short h8[8], l8[8];
    #pragma unroll
    for (int j = 0; j < 8; ++j) {
        const int k = kc * 32 + g * 8 + j;
        const float w = (k < 750 && n < N) ? W[(size_t)k * N + n] : 0.f;
        const unsigned short h = f2bf(w);
        h8[j] = h;
        l8[j] = f2bf(w - bf2f(h));
    }
    const size_t off = ((size_t)nb * 24 + kc) * 512 + (size_t)l * 8;
    #pragma unroll
    for (int j = 0; j < 8; ++j) { Phi[off + j] = h8[j]; Plo[off + j] = l8[j]; }
}

// ---------------- persistent recurrence: all 24*6 layers in one kernel ----------------
// Base = r9 (proven: 13us/step, canary exact). ROW-PER-XCD: XCD x owns rows x*64..+63;
// state never crosses an XCD (plain stores -> XCD L2; sc0 loads). Grid 256 x 384; 80KB
// LDS pad => 1 block/CU => exact pigeonhole 32 blocks/XCD (HW XCC_ID ticket). Block j:
// quarter=j>>3 (16 rows), p=j&7; wave w -> column task p*6+w of 48.
// r11's ONE change: REGISTER-SAFE bulk prefetch of the NEXT layer's panel. r9 counters
// showed B-stream demand-misses to LLC (~600cy, ~16/wave in flight) = the step time.
// After the epilogue each block loads 3x4B per thread covering its exclusive 960-line
// slice (32 blocks/XCD = full 3.93MB panel/XCD) into THREE NAMED REGISTERS that stay
// live across an explicit vmcnt(0) + asm sink -> no register-clobber hazard (the r10
// untracked-load bug), no extra drain (syncthreads emits vmcnt(0) there anyway).
// ~36K concurrent fills/XCD land at LLC BW during epilogue+barrier; next step's B loads
// become ~200cy L2 hits. Barrier: r9's proven agent-scope RMW-arrive + RO-release.
// Per-output MFMA order identical to r3..r9 => absmax canary 2.441e-4 must hold.
__launch_bounds__(384)
__global__ void recurrence(RecArgs A)
{
    __shared__ __align__(16) unsigned char lds[81920];   // 48KB used; 80KB forces 1 block/CU
    __shared__ int s_j;
    const int tid = threadIdx.x;

    int xcd;
    asm volatile("s_getreg_b32 %0, hwreg(HW_REG_XCC_ID)" : "=s"(xcd));
    xcd &= 7;
    if (tid == 0) s_j = (int)atomicAdd(A.ticket + xcd, 1u);
    __syncthreads();
    const int j = s_j;                   // 0..31 within this XCD (exact pigeonhole)
    const int quarter = j >> 3, p = j & 7;
    const int m0 = xcd * 64 + quarter * 16;

    const int w  = tid >> 6;             // wave 0..5
    const int l6 = tid & 63;
    const int g = l6 >> 4, c = l6 & 15;
    const int asw = (c & 7) << 4;        // FRAG XOR bits (row&7 == c&7)

    const int tk = p * 6 + w;            // column task 0..47
    const bool ispair = (tk < 32);
    const int su = ispair ? tk : (tk - 32);
    const int col = su * 16 + c;         // pair: m-col (valid<500); sv: x-col (valid<250)

    const size_t lnoff = (size_t)l6 * 8;
    const size_t bofs0 = ((size_t)((ispair ? tk : 64 + su) * 24)) * 512 + lnoff;
    const size_t bofs1 = ((size_t)((32 + tk) * 24)) * 512 + lnoff;   // pair only

    unsigned* cntw = A.cnt + (xcd << 5);
    unsigned* relw = A.rel + (xcd << 5);

    // prefetch line indices (block-exclusive slice of the 30720-line panel)
    const int li0 = j * 960 + tid;
    const int li1 = li0 + 384;
    const int li2 = j * 960 + 768 + ((tid < 192) ? tid : (tid - 192));  // dup for tid>=192 (harmless)

    float mreg[4];
    #pragma unroll
    for (int i = 0; i < 4; ++i) mreg[i] = 0.f;

#define FRAG(pl, kc) (*(const bf16x8*)(lds + (pl) * 24576 + c * 1536 + ((((kc) * 64) + g * 16) ^ asw)))

    #pragma unroll 1
    for (int step = 0; step < NSTEP; ++step) {
        const int tt = step / 6;
        const int l = step - 6 * tt;
        const unsigned* Ain = (step & 1) ? A.A1 : A.A0;
        unsigned* Aout      = (step & 1) ? A.A0 : A.A1;
        const unsigned short* Phi = A.Pw + (size_t)l * 2 * PL;
        const unsigned short* Plo = Phi + PL;
        const bool more = (step != NSTEP - 1);
        const int sn = step + 1;
        const int ln = sn - 6 * (sn / 6);

        // ---- stage A rows [m0, m0+16): 16 rows x 3072B = 3072 16B-chunks / 384 thr = 8
        // coalesced sc0 dwordx4 loads per thread; explicit vmcnt fence; unpack hi/lo.
        {
            const unsigned char* src = (const unsigned char*)(Ain + (size_t)m0 * SS);
            u32x4 tmp[8];
            #pragma unroll
            for (int jj = 0; jj < 8; ++jj) {
                const int f = tid + jj * 384;
                const int row = f / 192;
                const int q = f - row * 192;
                tmp[jj] = ld16_sc0(src + row * 3072 + q * 16);
            }
            asm volatile("s_waitcnt vmcnt(0)" ::: "memory");
            __builtin_amdgcn_sched_barrier(0);
            #pragma unroll
            for (int jj = 0; jj < 8; ++jj) {
                const int f = tid + jj * 384;
                const int row = f / 192;
                const int q = f - row * 192;
                const int d = row * 1536 + ((q * 8) ^ ((row & 7) << 4));
                const u32x4 v = tmp[jj];
                const unsigned h0 = (v[0] & 0xffffu) | (v[1] << 16);
                const unsigned h1 = (v[2] & 0xffffu) | (v[3] << 16);
                const unsigned o0 = (v[0] >> 16) | (v[1] & 0xffff0000u);
                const unsigned o1 = (v[2] >> 16) | (v[3] & 0xffff0000u);
                *(unsigned long long*)(lds + d)         = (unsigned long long)h0 | ((unsigned long long)h1 << 32);
                *(unsigned long long*)(lds + 24576 + d) = (unsigned long long)o0 | ((unsigned long long)o1 << 32);
            }
        }
        __syncthreads();

        if (ispair) {
            f32x4 z0 = (f32x4)0.f, z1 = (f32x4)0.f;
            #pragma unroll 4
            for (int kc = 0; kc < 24; ++kc) {
                const bf16x8 ah = FRAG(0, kc);
                const bf16x8 al = FRAG(1, kc);
                const size_t k5 = (size_t)kc * 512;
                const bf16x8 bh0 = LD8(Phi + bofs0 + k5);
                const bf16x8 bl0 = LD8(Plo + bofs0 + k5);
                const bf16x8 bh1 = LD8(Phi + bofs1 + k5);
                const bf16x8 bl1 = LD8(Plo + bofs1 + k5);
                z0 = mm(ah, bh0, z0); z0 = mm(al, bh0, z0); z0 = mm(ah, bl0, z0);
                z1 = mm(ah, bh1, z1); z1 = mm(al, bh1, z1); z1 = mm(ah, bl1, z1);
            }
            if (col < 500) {
                const float* bswp  = l ? A.b_sw  + (size_t)(l - 1) * 500 : A.b1_sw;
                const float* bmemp = l ? A.b_mem + (size_t)(l - 1) * 500 : A.b1_mem;
                const float bs = bswp[col];
                const float bm = bmemp[col];
                #pragma unroll
                for (int r = 0; r < 4; ++r) {
                    const int row = m0 + g * 4 + r;
                    float zs = z0[r] + bs;
                    float zm = z1[r] + bm;
                    if (l == 0) {
                        const int lt = A.letters[row * NT + tt];
                        zs += A.w1_sw[(size_t)(750 + lt) * 500 + col];
                        zm += A.w1_mem[(size_t)(750 + lt) * 500 + col];
                    }
                    const float s = 1.f / (1.f + expf(-zs));
                    const float mn = mreg[r] * s + tanhf(zm) * (1.f - s);
                    mreg[r] = mn;
                    const size_t o = (size_t)row * SS + 250 + col;
                    const unsigned short h = f2bf(mn);
                    const unsigned short lo2 = f2bf(mn - bf2f(h));
                    Aout[o] = (unsigned)h | ((unsigned)lo2 << 16);   // plain store -> XCD L2
                    if (step == NSTEP - 1) A.Sfin[o] = mn;
                }
            }
        } else {
            f32x4 z0 = (f32x4)0.f;
            #pragma unroll 4
            for (int kc = 0; kc < 24; ++kc) {
                const bf16x8 ah = FRAG(0, kc);
                const bf16x8 al = FRAG(1, kc);
                const size_t k5 = (size_t)kc * 512;
                const bf16x8 bh = LD8(Phi + bofs0 + k5);
                const bf16x8 bl = LD8(Plo + bofs0 + k5);
                z0 = mm(ah, bh, z0); z0 = mm(al, bh, z0); z0 = mm(ah, bl, z0);
            }
            if (col < 250) {
                const float* bsvp = l ? A.b_sv + (size_t)(l - 1) * 250 : A.b1_sv;
                const float bv = bsvp[col];
                #pragma unroll
                for (int r = 0; r < 4; ++r) {
                    const int row = m0 + g * 4 + r;
                    float z = z0[r] + bv;
                    if (l == 0) {
                        const int lt = A.letters[row * NT + tt];
                        z += A.w1_sv[(size_t)(750 + lt) * 250 + col];
                    }
                    const float x = tanhf(z);
                    const size_t o = (size_t)row * SS + col;
                    const unsigned short h = f2bf(x);
                    const unsigned short lo2 = f2bf(x - bf2f(h));
                    Aout[o] = (unsigned)h | ((unsigned)lo2 << 16);   // plain store -> XCD L2
                    if (step == NSTEP - 1) A.Sfin[o] = x;
                }
            }
        }

        // ---- bulk prefetch of NEXT layer's panel into this XCD's L2 (register-safe) ----
        // 3 x 4B loads/thread into NAMED registers, kept live across an explicit vmcnt(0)
        // and consumed by an asm sink -> no clobber hazard; the vmcnt drain coincides with
        // the one __syncthreads emits anyway. Fills overlap the epilogue + barrier window.
        if (more) {
            const unsigned char* np = (const unsigned char*)(A.Pw + (size_t)ln * 2 * PL);
            const unsigned char* p0 = np + ((size_t)li0 << 7);
            const unsigned char* p1 = np + ((size_t)li1 << 7);
            const unsigned char* p2 = np + ((size_t)li2 << 7);
            unsigned pf0, pf1, pf2;
            asm volatile("global_load_dword %0, %3, off\n\t"
                         "global_load_dword %1, %4, off\n\t"
                         "global_load_dword %2, %5, off"
                         : "=&v"(pf0), "=&v"(pf1), "=&v"(pf2)
                         : "v"(p0), "v"(p1), "v"(p2));
            asm volatile("s_waitcnt vmcnt(0)" ::: "memory");
            asm volatile("" :: "v"(pf0), "v"(pf1), "v"(pf2));
        }

        // ---- per-XCD barrier (r9-proven agent-scope form): 32 RMW arrivals + release ----
        __syncthreads();
        if (more) {
            if (tid == 0) {
                const unsigned v = __hip_atomic_fetch_add(cntw, 1u, __ATOMIC_RELAXED, __HIP_MEMORY_SCOPE_AGENT);
                if (v == 32u * (unsigned)(step + 1) - 1u) {
                    __hip_atomic_store(relw, (unsigned)(step + 1), __ATOMIC_RELAXED, __HIP_MEMORY_SCOPE_AGENT);
                } else {
                    while (__hip_atomic_load(relw, __ATOMIC_RELAXED, __HIP_MEMORY_SCOPE_AGENT) < (unsigned)(step + 1))
                        __builtin_amdgcn_s_sleep(2);
                }
            }
            __syncthreads();
        }
    }
#undef FRAG
}

// ---------------- head GEMM: Y = tanh(X @ W + b) (fp32) ----------------
__launch_bounds__(128)
__global__ void head_gemm(const float* __restrict__ X, int ldx, int K,
                          const float* __restrict__ W, const float* __restrict__ bias,
                          float* __restrict__ Y, int N)
{
    const int tid = threadIdx.x;
    const int m0 = blockIdx.y * 32;
    const int n0 = blockIdx.x * 64;

    __shared__ float As[2][32][36];
    __shared__ float Bs[2][32][68];

    const int tx = tid & 15, ty = tid >> 4;
    const int kl = tid & 31, rl = tid >> 5;
    const int cl = tid & 63, kg = tid >> 6;
    const bool cok = (n0 + cl) < N;

    float acc[4][4] = {{0.f}};
    float ar[8], br[16];

    {
        const float* a = X + (size_t)(m0 + rl) * ldx + kl;
        #pragma unroll
        for (int i = 0; i < 8; i++) ar[i] = a[(size_t)(4 * i) * ldx];
        #pragma unroll
        for (int i = 0; i < 16; i++)
            br[i] = cok ? W[(size_t)(kg + 2 * i) * N + n0 + cl] : 0.f;
        #pragma unroll
        for (int i = 0; i < 8; i++) As[0][kl][rl + 4 * i] = ar[i];
        #pragma unroll
        for (int i = 0; i < 16; i++) Bs[0][kg + 2 * i][cl] = br[i];
    }
    __syncthreads();

    int buf = 0;
    const int NK = (K + 31) / 32;
    #pragma unroll 1
    for (int kt = 0; kt < NK; kt++) {
        const bool more = (kt + 1 < NK);
        if (more) {
            const int k0 = (kt + 1) * 32;
            const bool ka = (k0 + kl) < K;
            const float* a = X + (size_t)(m0 + rl) * ldx + k0 + kl;
            #pragma unroll
            for (int i = 0; i < 8; i++) ar[i] = ka ? a[(size_t)(4 * i) * ldx] : 0.f;
            #pragma unroll
            for (int i = 0; i < 16; i++) {
                const int kk = k0 + kg + 2 * i;
                br[i] = (cok && kk < K) ? W[(size_t)kk * N + n0 + cl] : 0.f;
            }
        }
        #pragma unroll
        for (int kk = 0; kk < 32; kk++) {
            float4 av = *(const float4*)&As[buf][kk][ty * 4];
            float4 bv = *(const float4*)&Bs[buf][kk][tx * 4];
            const float aa[4] = {av.x, av.y, av.z, av.w};
            const float bb[4] = {bv.x, bv.y, bv.z, bv.w};
            #pragma unroll
            for (int i = 0; i < 4; i++)
                #pragma unroll
                for (int j = 0; j < 4; j++)
                    acc[i][j] = fmaf(aa[i], bb[j], acc[i][j]);
        }
        if (more) {
            #pragma unroll
            for (int i = 0; i < 8; i++) As[buf ^ 1][kl][rl + 4 * i] = ar[i];
            #pragma unroll
            for (int i = 0; i < 16; i++) Bs[buf ^ 1][kg + 2 * i][cl] = br[i];
            __syncthreads();
            buf ^= 1;
        }
    }

    #pragma unroll
    for (int i = 0; i < 4; i++) {
        const int b = m0 + ty * 4 + i;
        #pragma unroll
        for (int j = 0; j < 4; j++) {
            const int n = n0 + tx * 4 + j;
            if (n < N) Y[(size_t)b * N + n] = tanhf(acc[i][j] + bias[n]);
        }
    }
}

// ---------------- final: logits (K=100, N=30) + softmax ----------------
__global__ void head_final(const float* __restrict__ Y4, const float* __restrict__ W,
                           const float* __restrict__ bias, float* __restrict__ out)
{
    const int row = blockIdx.x;
    __shared__ float y[100];
    __shared__ float z[NV];
    for (int k = threadIdx.x; k < 100; k += 64) y[k] = Y4[row * 100 + k];
    __syncthreads();
    const int n = threadIdx.x;
    if (n < NV) {
        float acc = bias[n];
        for (int k = 0; k < 100; k++) acc = fmaf(y[k], W[k * NV + n], acc);
        z[n] = acc;
    }
    __syncthreads();
    if (n < NV) {
        float mx = -1e30f;
        for (int i = 0; i < NV; i++) mx = fmaxf(mx, z[i]);
        float sum = 0.f;
        for (int i = 0; i < NV; i++) sum += expf(z[i] - mx);
        out[row * NV + n] = expf(z[n] - mx) / sum;
    }
}

extern "C" void kernel_launch(void* const* d_in, const int* in_sizes, int n_in,
                              void* d_out, int out_size, void* d_ws, size_t ws_size,
                              hipStream_t stream)
{
    const int*   letters = (const int*)  d_in[0];
    const float* w1_sv   = (const float*)d_in[1];
    const float* b1_sv   = (const float*)d_in[2];
    const float* w1_mem  = (const float*)d_in[3];
    const float* b1_mem  = (const float*)d_in[4];
    const float* w1_sw   = (const float*)d_in[5];
    const float* b1_sw   = (const float*)d_in[6];
    const float* w_sv    = (const float*)d_in[7];
    const float* b_sv    = (const float*)d_in[8];
    const float* w_mem   = (const float*)d_in[9];
    const float* b_mem   = (const float*)d_in[10];
    const float* w_sw    = (const float*)d_in[11];
    const float* b_sw    = (const float*)d_in[12];
    const float* wp1 = (const float*)d_in[13]; const float* bp1 = (const float*)d_in[14];
    const float* wp2 = (const float*)d_in[15]; const float* bp2 = (const float*)d_in[16];
    const float* wp3 = (const float*)d_in[17]; const float* bp3 = (const float*)d_in[18];
    const float* wp4 = (const float*)d_in[19]; const float* bp4 = (const float*)d_in[20];
    const float* wp5 = (const float*)d_in[21]; const float* bp5 = (const float*)d_in[22];

    // workspace layout
    float* Sfin = (float*)d_ws;                                   // BSZ*SS f32 (written at final step)
    float* cntf = Sfin + (size_t)BSZ * SS;                        // 1024 u32: cnt[8x32], rel[8x32], ticket[8]
    unsigned int* cnt = (unsigned int*)cntf;
    unsigned int* rel = cnt + 256;
    unsigned int* ticket = cnt + 512;
    unsigned* A0 = (unsigned*)(cntf + 1024);                      // interleaved state plane 0
    unsigned* A1 = A0 + (size_t)BSZ * SS;                         // interleaved state plane 1
    unsigned short* Pw = (unsigned short*)(A1 + (size_t)BSZ * SS);// 12 * PL ushorts
    float* Y1 = (float*)(Pw + (size_t)12 * PL);
    float* Y2 = Y1 + (size_t)BSZ * 450;
    float* Y3 = Y2 + (size_t)BSZ * 300;
    float* Y4 = Y3 + (size_t)BSZ * 200;

    // zero barrier words + tickets + both interleaved state planes (pad cols stay 0 forever)
    zero_kernel<<<512, 256, 0, stream>>>(cntf, 1024 + 2 * BSZ * SS);

    // one-time weight packing
    pack_weights<<<dim3(24, 80), 64, 0, stream>>>(w1_sw, w1_mem, w1_sv, Pw, Pw + PL);
    for (int l = 1; l < 6; ++l)
        pack_weights<<<dim3(24, 80), 64, 0, stream>>>(
            w_sw  + (size_t)(l - 1) * 750 * 500,
            w_mem + (size_t)(l - 1) * 750 * 500,
            w_sv  + (size_t)(l - 1) * 750 * 250,
            Pw + (size_t)l * 2 * PL, Pw + (size_t)l * 2 * PL + PL);

    RecArgs ra;
    ra.Pw = Pw;
    ra.A0 = A0; ra.A1 = A1;
    ra.Sfin = Sfin; ra.cnt = cnt; ra.rel = rel; ra.ticket = ticket;
    ra.b1_sw = b1_sw; ra.b1_mem = b1_mem; ra.b1_sv = b1_sv;
    ra.b_sw = b_sw;   ra.b_mem = b_mem;   ra.b_sv = b_sv;
    ra.w1_sw = w1_sw; ra.w1_mem = w1_mem; ra.w1_sv = w1_sv;
    ra.letters = letters;
    recurrence<<<NBLK, 384, 0, stream>>>(ra);

    head_gemm<<<dim3(8, 16), 128, 0, stream>>>(Sfin, SS, 750, wp1, bp1, Y1, 450);
    head_gemm<<<dim3(5, 16), 128, 0, stream>>>(Y1, 450, 450, wp2, bp2, Y2, 300);
    head_gemm<<<dim3(4, 16), 128, 0, stream>>>(Y2, 300, 300, wp3, bp3, Y3, 200);
    head_gemm<<<dim3(2, 16), 128, 0, stream>>>(Y3, 200, 200, wp4, bp4, Y4, 100);
    head_final<<<BSZ, 64, 0, stream>>>(Y4, wp5, bp5, (float*)d_out);
}

// Round 12
// 2143.996 us; speedup vs baseline: 1.0027x; 1.0027x over previous
//
#include <hip/hip_runtime.h>
#include <math.h>

#define BSZ 512
#define NV 30
#define NT 24
#define SS 768                  // state row stride (x: 0..249, m: 250..749, pad: 750..767)
#define PL (80 * 24 * 512)      // packed ushorts per (layer, half): 80 nb-blocks x 24 kc x 512
#define NBLK 256
#define NSTEP 144

typedef __attribute__((ext_vector_type(8))) short bf16x8;
typedef __attribute__((ext_vector_type(4))) float f32x4;
typedef __attribute__((ext_vector_type(4))) unsigned u32x4;

__device__ __forceinline__ unsigned short f2bf(float f) {
    unsigned u = __float_as_uint(f);
    u += 0x7fffu + ((u >> 16) & 1u);        // round-to-nearest-even
    return (unsigned short)(u >> 16);
}
__device__ __forceinline__ float bf2f(unsigned short h) {
    return __uint_as_float(((unsigned)h) << 16);
}
__device__ __forceinline__ f32x4 mm(bf16x8 a, bf16x8 b, f32x4 c) {
    return __builtin_amdgcn_mfma_f32_16x16x32_bf16(a, b, c, 0, 0, 0);
}
#define LD8(p) (*(const bf16x8*)(const void*)(p))

// coalesced 16B load, L1-bypass (sc0); result valid only after explicit vmcnt fence.
__device__ __forceinline__ u32x4 ld16_sc0(const void* p) {
    u32x4 r;
    asm volatile("global_load_dwordx4 %0, %1, off sc0" : "=v"(r) : "v"(p) : "memory");
    return r;
}

struct RecArgs {
    const unsigned short* Pw;
    unsigned* A0; unsigned* A1;      // interleaved state planes: elem = hi | (lo<<16)
    float* Sfin;
    unsigned int* cnt;               // per-XCD barrier counters, stride 32 u32
    unsigned int* rel;               // per-XCD release words, stride 32 u32
    unsigned int* ticket;            // per-XCD tickets [8]
    const float* b1_sw; const float* b1_mem; const float* b1_sv;
    const float* b_sw;  const float* b_mem;  const float* b_sv;
    const float* w1_sw; const float* w1_mem; const float* w1_sv;
    const int* letters;
};

// ---------------- zero ----------------
__global__ void zero_kernel(float* p, int n) {
    int i = blockIdx.x * blockDim.x + threadIdx.x;
    int st = gridDim.x * blockDim.x;
    for (; i < n; i += st) p[i] = 0.f;
}

// ---------------- one-time weight pack (ALL 6 layers, one launch): fp32 -> hi/lo bf16 MFMA-B ----
// Phi[((nb*24 + kc)*64 + lane)*8 + j] = bf16_hi(W[kc*32 + (lane>>4)*8 + j][nb*16 + (lane&15)])
// nb 0..31 = sw (N=500 pad 512), 32..63 = mem, 64..79 = sv (N=250 pad 256). k>=750 zero-padded.
__launch_bounds__(64)
__global__ void pack_weights_all(const float* __restrict__ w1_sw, const float* __restrict__ w1_mem,
                                 const float* __restrict__ w1_sv,
                                 const float* __restrict__ w_sw, const float* __restrict__ w_mem,
                                 const float* __restrict__ w_sv,
                                 unsigned short* __restrict__ Pw)
{
    const int kc = blockIdx.x;   // 0..23
    const int nb = blockIdx.y;   // 0..79
    const int lyr = blockIdx.z;  // 0..5
    const int l  = threadIdx.x;  // 0..63
    const int g = l >> 4, c = l & 15;
    const float *Wsw, *Wmem, *Wsv;
    if (lyr == 0) { Wsw = w1_sw; Wmem = w1_mem; Wsv = w1_sv; }
    else {
        Wsw  = w_sw  + (size_t)(lyr - 1) * 750 * 500;
        Wmem = w_mem + (size_t)(lyr - 1) * 750 * 500;
        Wsv  = w_sv  + (size_t)(lyr - 1) * 750 * 250;
    }
    unsigned short* Phi = Pw + (size_t)lyr * 2 * PL;
    unsigned short* Plo = Phi + PL;
    const float* W; int N, nbl;
    if (nb < 32)      { W = Wsw;  N = 500; nbl = nb; }
    else if (nb < 64) { W = Wmem; N = 500; nbl = nb - 32; }
    else              { W = Wsv;  N = 250; nbl = nb - 64; }
    const int n = nbl * 16 + c;
    unsigned short h8[8], l8[8];
    #pragma unroll
    for (int j = 0; j < 8; ++j) {
        const int k = kc * 32 + g * 8 + j;
        const float w = (k < 750 && n < N) ? W[(size_t)k * N + n] : 0.f;
        const unsigned short h = f2bf(w);
        h8[j] = h;
        l8[j] = f2bf(w - bf2f(h));
    }
    const size_t off = ((size_t)nb * 24 + kc) * 512 + (size_t)l * 8;
    #pragma unroll
    for (int j = 0; j < 8; ++j) { Phi[off + j] = h8[j]; Plo[off + j] = l8[j]; }
}

// ---------------- persistent recurrence: all 24*6 layers in one kernel ----------------
// Base = r9 (proven: 13us/step, canary exact). ROW-PER-XCD: XCD x owns rows x*64..+63;
// state never crosses an XCD (plain stores -> XCD L2; sc0 loads). Grid 256 x 384; 80KB
// LDS pad => 1 block/CU => exact pigeonhole 32 blocks/XCD (HW XCC_ID ticket). Block j:
// quarter=j>>3 (16 rows), p=j&7; wave w -> column task p*6+w of 48.
// r12's ONE mechanism change: UNLOCK THE VGPR BUDGET. r9/r11 compiled at VGPR=88
// (default occupancy-targeting), which caps outstanding B-loads at ~5 -> the 96
// LLC-latency loads/wave serialize into ~6-7us of exposed latency = the step time
// (r11 falsified the cache-state theory: prefetch filled L2, time unchanged ->
// issue-pipeline-bound, not cache-bound). Occupancy is FIXED at 6 waves/CU by the
// 80KB LDS pad, so waves/SIMD=1.5 and ~340 VGPRs/wave are free: launch_bounds(384,1)
// lifts the cap and full unroll of the 24-iter kc loop lets the scheduler hoist
// 30-40 loads deep. MFMA sequence per output unchanged => absmax 2.441e-4 must hold.
__launch_bounds__(384, 1)
__global__ void recurrence(RecArgs A)
{
    __shared__ __align__(16) unsigned char lds[81920];   // 48KB used; 80KB forces 1 block/CU
    __shared__ int s_j;
    const int tid = threadIdx.x;

    int xcd;
    asm volatile("s_getreg_b32 %0, hwreg(HW_REG_XCC_ID)" : "=s"(xcd));
    xcd &= 7;
    if (tid == 0) s_j = (int)atomicAdd(A.ticket + xcd, 1u);
    __syncthreads();
    const int j = s_j;                   // 0..31 within this XCD (exact pigeonhole)
    const int quarter = j >> 3, p = j & 7;
    const int m0 = xcd * 64 + quarter * 16;

    const int w  = tid >> 6;             // wave 0..5
    const int l6 = tid & 63;
    const int g = l6 >> 4, c = l6 & 15;
    const int asw = (c & 7) << 4;        // FRAG XOR bits (row&7 == c&7)

    const int tk = p * 6 + w;            // column task 0..47
    const bool ispair = (tk < 32);
    const int su = ispair ? tk : (tk - 32);
    const int col = su * 16 + c;         // pair: m-col (valid<500); sv: x-col (valid<250)

    const size_t lnoff = (size_t)l6 * 8;
    const size_t bofs0 = ((size_t)((ispair ? tk : 64 + su) * 24)) * 512 + lnoff;
    const size_t bofs1 = ((size_t)((32 + tk) * 24)) * 512 + lnoff;   // pair only

    unsigned* cntw = A.cnt + (xcd << 5);
    unsigned* relw = A.rel + (xcd << 5);

    float mreg[4];
    #pragma unroll
    for (int i = 0; i < 4; ++i) mreg[i] = 0.f;

#define FRAG(pl, kc) (*(const bf16x8*)(lds + (pl) * 24576 + c * 1536 + ((((kc) * 64) + g * 16) ^ asw)))

    #pragma unroll 1
    for (int step = 0; step < NSTEP; ++step) {
        const int tt = step / 6;
        const int l = step - 6 * tt;
        const unsigned* Ain = (step & 1) ? A.A1 : A.A0;
        unsigned* Aout      = (step & 1) ? A.A0 : A.A1;
        const unsigned short* Phi = A.Pw + (size_t)l * 2 * PL;
        const unsigned short* Plo = Phi + PL;
        const bool more = (step != NSTEP - 1);

        // ---- stage A rows [m0, m0+16): 16 rows x 3072B = 3072 16B-chunks / 384 thr = 8
        // coalesced sc0 dwordx4 loads per thread; explicit vmcnt fence; unpack hi/lo.
        {
            const unsigned char* src = (const unsigned char*)(Ain + (size_t)m0 * SS);
            u32x4 tmp[8];
            #pragma unroll
            for (int jj = 0; jj < 8; ++jj) {
                const int f = tid + jj * 384;
                const int row = f / 192;
                const int q = f - row * 192;
                tmp[jj] = ld16_sc0(src + row * 3072 + q * 16);
            }
            asm volatile("s_waitcnt vmcnt(0)" ::: "memory");
            __builtin_amdgcn_sched_barrier(0);
            #pragma unroll
            for (int jj = 0; jj < 8; ++jj) {
                const int f = tid + jj * 384;
                const int row = f / 192;
                const int q = f - row * 192;
                const int d = row * 1536 + ((q * 8) ^ ((row & 7) << 4));
                const u32x4 v = tmp[jj];
                const unsigned h0 = (v[0] & 0xffffu) | (v[1] << 16);
                const unsigned h1 = (v[2] & 0xffffu) | (v[3] << 16);
                const unsigned o0 = (v[0] >> 16) | (v[1] & 0xffff0000u);
                const unsigned o1 = (v[2] >> 16) | (v[3] & 0xffff0000u);
                *(unsigned long long*)(lds + d)         = (unsigned long long)h0 | ((unsigned long long)h1 << 32);
                *(unsigned long long*)(lds + 24576 + d) = (unsigned long long)o0 | ((unsigned long long)o1 << 32);
            }
        }
        __syncthreads();

        if (ispair) {
            f32x4 z0 = (f32x4)0.f, z1 = (f32x4)0.f;
            #pragma unroll
            for (int kc = 0; kc < 24; ++kc) {
                const bf16x8 ah = FRAG(0, kc);
                const bf16x8 al = FRAG(1, kc);
                const size_t k5 = (size_t)kc * 512;
                const bf16x8 bh0 = LD8(Phi + bofs0 + k5);
                const bf16x8 bl0 = LD8(Plo + bofs0 + k5);
                const bf16x8 bh1 = LD8(Phi + bofs1 + k5);
                const bf16x8 bl1 = LD8(Plo + bofs1 + k5);
                z0 = mm(ah, bh0, z0); z0 = mm(al, bh0, z0); z0 = mm(ah, bl0, z0);
                z1 = mm(ah, bh1, z1); z1 = mm(al, bh1, z1); z1 = mm(ah, bl1, z1);
            }
            if (col < 500) {
                const float* bswp  = l ? A.b_sw  + (size_t)(l - 1) * 500 : A.b1_sw;
                const float* bmemp = l ? A.b_mem + (size_t)(l - 1) * 500 : A.b1_mem;
                const float bs = bswp[col];
                const float bm = bmemp[col];
                #pragma unroll
                for (int r = 0; r < 4; ++r) {
                    const int row = m0 + g * 4 + r;
                    float zs = z0[r] + bs;
                    float zm = z1[r] + bm;
                    if (l == 0) {
                        const int lt = A.letters[row * NT + tt];
                        zs += A.w1_sw[(size_t)(750 + lt) * 500 + col];
                        zm += A.w1_mem[(size_t)(750 + lt) * 500 + col];
                    }
                    const float s = 1.f / (1.f + expf(-zs));
                    const float mn = mreg[r] * s + tanhf(zm) * (1.f - s);
                    mreg[r] = mn;
                    const size_t o = (size_t)row * SS + 250 + col;
                    const unsigned short h = f2bf(mn);
                    const unsigned short lo2 = f2bf(mn - bf2f(h));
                    Aout[o] = (unsigned)h | ((unsigned)lo2 << 16);   // plain store -> XCD L2
                    if (step == NSTEP - 1) A.Sfin[o] = mn;
                }
            }
        } else {
            f32x4 z0 = (f32x4)0.f;
            #pragma unroll
            for (int kc = 0; kc < 24; ++kc) {
                const bf16x8 ah = FRAG(0, kc);
                const bf16x8 al = FRAG(1, kc);
                const size_t k5 = (size_t)kc * 512;
                const bf16x8 bh = LD8(Phi + bofs0 + k5);
                const bf16x8 bl = LD8(Plo + bofs0 + k5);
                z0 = mm(ah, bh, z0); z0 = mm(al, bh, z0); z0 = mm(ah, bl, z0);
            }
            if (col < 250) {
                const float* bsvp = l ? A.b_sv + (size_t)(l - 1) * 250 : A.b1_sv;
                const float bv = bsvp[col];
                #pragma unroll
                for (int r = 0; r < 4; ++r) {
                    const int row = m0 + g * 4 + r;
                    float z = z0[r] + bv;
                    if (l == 0) {
                        const int lt = A.letters[row * NT + tt];
                        z += A.w1_sv[(size_t)(750 + lt) * 250 + col];
                    }
                    const float x = tanhf(z);
                    const size_t o = (size_t)row * SS + col;
                    const unsigned short h = f2bf(x);
                    const unsigned short lo2 = f2bf(x - bf2f(h));
                    Aout[o] = (unsigned)h | ((unsigned)lo2 << 16);   // plain store -> XCD L2
                    if (step == NSTEP - 1) A.Sfin[o] = x;
                }
            }
        }

        // ---- per-XCD barrier (r9-proven agent-scope form): 32 RMW arrivals + release ----
        __syncthreads();
        if (more) {
            if (tid == 0) {
                const unsigned v = __hip_atomic_fetch_add(cntw, 1u, __ATOMIC_RELAXED, __HIP_MEMORY_SCOPE_AGENT);
                if (v == 32u * (unsigned)(step + 1) - 1u) {
                    __hip_atomic_store(relw, (unsigned)(step + 1), __ATOMIC_RELAXED, __HIP_MEMORY_SCOPE_AGENT);
                } else {
                    while (__hip_atomic_load(relw, __ATOMIC_RELAXED, __HIP_MEMORY_SCOPE_AGENT) < (unsigned)(step + 1))
                        __builtin_amdgcn_s_sleep(2);
                }
            }
            __syncthreads();
        }
    }
#undef FRAG
}

// ---------------- head GEMM: Y = tanh(X @ W + b) (fp32) ----------------
__launch_bounds__(128)
__global__ void head_gemm(const float* __restrict__ X, int ldx, int K,
                          const float* __restrict__ W, const float* __restrict__ bias,
                          float* __restrict__ Y, int N)
{
    const int tid = threadIdx.x;
    const int m0 = blockIdx.y * 32;
    const int n0 = blockIdx.x * 64;

    __shared__ float As[2][32][36];
    __shared__ float Bs[2][32][68];

    const int tx = tid & 15, ty = tid >> 4;
    const int kl = tid & 31, rl = tid >> 5;
    const int cl = tid & 63, kg = tid >> 6;
    const bool cok = (n0 + cl) < N;

    float acc[4][4] = {{0.f}};
    float ar[8], br[16];

    {
        const float* a = X + (size_t)(m0 + rl) * ldx + kl;
        #pragma unroll
        for (int i = 0; i < 8; i++) ar[i] = a[(size_t)(4 * i) * ldx];
        #pragma unroll
        for (int i = 0; i < 16; i++)
            br[i] = cok ? W[(size_t)(kg + 2 * i) * N + n0 + cl] : 0.f;
        #pragma unroll
        for (int i = 0; i < 8; i++) As[0][kl][rl + 4 * i] = ar[i];
        #pragma unroll
        for (int i = 0; i < 16; i++) Bs[0][kg + 2 * i][cl] = br[i];
    }
    __syncthreads();

    int buf = 0;
    const int NK = (K + 31) / 32;
    #pragma unroll 1
    for (int kt = 0; kt < NK; kt++) {
        const bool more = (kt + 1 < NK);
        if (more) {
            const int k0 = (kt + 1) * 32;
            const bool ka = (k0 + kl) < K;
            const float* a = X + (size_t)(m0 + rl) * ldx + k0 + kl;
            #pragma unroll
            for (int i = 0; i < 8; i++) ar[i] = ka ? a[(size_t)(4 * i) * ldx] : 0.f;
            #pragma unroll
            for (int i = 0; i < 16; i++) {
                const int kk = k0 + kg + 2 * i;
                br[i] = (cok && kk < K) ? W[(size_t)kk * N + n0 + cl] : 0.f;
            }
        }
        #pragma unroll
        for (int kk = 0; kk < 32; kk++) {
            float4 av = *(const float4*)&As[buf][kk][ty * 4];
            float4 bv = *(const float4*)&Bs[buf][kk][tx * 4];
            const float aa[4] = {av.x, av.y, av.z, av.w};
            const float bb[4] = {bv.x, bv.y, bv.z, bv.w};
            #pragma unroll
            for (int i = 0; i < 4; i++)
                #pragma unroll
                for (int j = 0; j < 4; j++)
                    acc[i][j] = fmaf(aa[i], bb[j], acc[i][j]);
        }
        if (more) {
            #pragma unroll
            for (int i = 0; i < 8; i++) As[buf ^ 1][kl][rl + 4 * i] = ar[i];
            #pragma unroll
            for (int i = 0; i < 16; i++) Bs[buf ^ 1][kg + 2 * i][cl] = br[i];
            __syncthreads();
            buf ^= 1;
        }
    }

    #pragma unroll
    for (int i = 0; i < 4; i++) {
        const int b = m0 + ty * 4 + i;
        #pragma unroll
        for (int j = 0; j < 4; j++) {
            const int n = n0 + tx * 4 + j;
            if (n < N) Y[(size_t)b * N + n] = tanhf(acc[i][j] + bias[n]);
        }
    }
}

// ---------------- final: logits (K=100, N=30) + softmax ----------------
__global__ void head_final(const float* __restrict__ Y4, const float* __restrict__ W,
                           const float* __restrict__ bias, float* __restrict__ out)
{
    const int row = blockIdx.x;
    __shared__ float y[100];
    __shared__ float z[NV];
    for (int k = threadIdx.x; k < 100; k += 64) y[k] = Y4[row * 100 + k];
    __syncthreads();
    const int n = threadIdx.x;
    if (n < NV) {
        float acc = bias[n];
        for (int k = 0; k < 100; k++) acc = fmaf(y[k], W[k * NV + n], acc);
        z[n] = acc;
    }
    __syncthreads();
    if (n < NV) {
        float mx = -1e30f;
        for (int i = 0; i < NV; i++) mx = fmaxf(mx, z[i]);
        float sum = 0.f;
        for (int i = 0; i < NV; i++) sum += expf(z[i] - mx);
        out[row * NV + n] = expf(z[n] - mx) / sum;
    }
}

extern "C" void kernel_launch(void* const* d_in, const int* in_sizes, int n_in,
                              void* d_out, int out_size, void* d_ws, size_t ws_size,
                              hipStream_t stream)
{
    const int*   letters = (const int*)  d_in[0];
    const float* w1_sv   = (const float*)d_in[1];
    const float* b1_sv   = (const float*)d_in[2];
    const float* w1_mem  = (const float*)d_in[3];
    const float* b1_mem  = (const float*)d_in[4];
    const float* w1_sw   = (const float*)d_in[5];
    const float* b1_sw   = (const float*)d_in[6];
    const float* w_sv    = (const float*)d_in[7];
    const float* b_sv    = (const float*)d_in[8];
    const float* w_mem   = (const float*)d_in[9];
    const float* b_mem   = (const float*)d_in[10];
    const float* w_sw    = (const float*)d_in[11];
    const float* b_sw    = (const float*)d_in[12];
    const float* wp1 = (const float*)d_in[13]; const float* bp1 = (const float*)d_in[14];
    const float* wp2 = (const float*)d_in[15]; const float* bp2 = (const float*)d_in[16];
    const float* wp3 = (const float*)d_in[17]; const float* bp3 = (const float*)d_in[18];
    const float* wp4 = (const float*)d_in[19]; const float* bp4 = (const float*)d_in[20];
    const float* wp5 = (const float*)d_in[21]; const float* bp5 = (const float*)d_in[22];

    // workspace layout
    float* Sfin = (float*)d_ws;                                   // BSZ*SS f32 (written at final step)
    float* cntf = Sfin + (size_t)BSZ * SS;                        // 1024 u32: cnt[8x32], rel[8x32], ticket[8]
    unsigned int* cnt = (unsigned int*)cntf;
    unsigned int* rel = cnt + 256;
    unsigned int* ticket = cnt + 512;
    unsigned* A0 = (unsigned*)(cntf + 1024);                      // interleaved state plane 0
    unsigned* A1 = A0 + (size_t)BSZ * SS;                         // interleaved state plane 1
    unsigned short* Pw = (unsigned short*)(A1 + (size_t)BSZ * SS);// 12 * PL ushorts
    float* Y1 = (float*)(Pw + (size_t)12 * PL);
    float* Y2 = Y1 + (size_t)BSZ * 450;
    float* Y3 = Y2 + (size_t)BSZ * 300;
    float* Y4 = Y3 + (size_t)BSZ * 200;

    // zero barrier words + tickets + both interleaved state planes (pad cols stay 0 forever)
    zero_kernel<<<512, 256, 0, stream>>>(cntf, 1024 + 2 * BSZ * SS);

    // one-time weight packing: single launch, all 6 layers
    pack_weights_all<<<dim3(24, 80, 6), 64, 0, stream>>>(w1_sw, w1_mem, w1_sv,
                                                         w_sw, w_mem, w_sv, Pw);

    RecArgs ra;
    ra.Pw = Pw;
    ra.A0 = A0; ra.A1 = A1;
    ra.Sfin = Sfin; ra.cnt = cnt; ra.rel = rel; ra.ticket = ticket;
    ra.b1_sw = b1_sw; ra.b1_mem = b1_mem; ra.b1_sv = b1_sv;
    ra.b_sw = b_sw;   ra.b_mem = b_mem;   ra.b_sv = b_sv;
    ra.w1_sw = w1_sw; ra.w1_mem = w1_mem; ra.w1_sv = w1_sv;
    ra.letters = letters;
    recurrence<<<NBLK, 384, 0, stream>>>(ra);

    head_gemm<<<dim3(8, 16), 128, 0, stream>>>(Sfin, SS, 750, wp1, bp1, Y1, 450);
    head_gemm<<<dim3(5, 16), 128, 0, stream>>>(Y1, 450, 450, wp2, bp2, Y2, 300);
    head_gemm<<<dim3(4, 16), 128, 0, stream>>>(Y2, 300, 300, wp3, bp3, Y3, 200);
    head_gemm<<<dim3(2, 16), 128, 0, stream>>>(Y3, 200, 200, wp4, bp4, Y4, 100);
    head_final<<<BSZ, 64, 0, stream>>>(Y4, wp5, bp5, (float*)d_out);
}